// Round 6
// baseline (341.604 us; speedup 1.0000x reference)
//
#include <hip/hip_runtime.h>

// Problem constants (from reference)
#define Fn 8
#define Bn 4

constexpr unsigned HW    = 720u * 1280u;                 // 921600
constexpr unsigned CHW   = 3u * HW;                      // 2764800
constexpr unsigned QUADS = CHW / 4u;                     // 691200
constexpr unsigned XB    = QUADS / 256u;                 // 2700 blocks per slice
constexpr unsigned OUT0  = Bn * 12u * HW;                // ce_blur_img_noisy elements
constexpr unsigned OUT1  = (unsigned)Bn * Fn * CHW * 2u; // ce_code_up_ elements
// out2 (ce_blur_img) follows at OUT0 + OUT1

typedef float f4 __attribute__((ext_vector_type(4)));

// One launch, 1D grid of 24300 blocks:
//   bid <  2700          : blur slice  — thread = quad, fat over b (reads cw once,
//                          codes packed to 2 x u32 bitmask, 64->2 VGPR)
//   bid >= 2700 (21600)  : bcast slice — thread = (quad, f), writes 4 broadcast copies
// Blur dispatched first (long pole); bcast's write stream fills HBM while blur
// waves wait on loads. cw is read by both slices but fetched from HBM ~once
// (177 MB fits L3; second reader hits cache).
__global__ __launch_bounds__(256) void cep_fused_kernel(const float* __restrict__ frames,
                                                        const float* __restrict__ cw,
                                                        float* __restrict__ out) {
    const unsigned bid = blockIdx.x;
    float* out1 = out + OUT0;          // ce_code_up_

    if (bid < XB) {
        // ----------------- blur slice -----------------
        const unsigned quad = bid * 256u + threadIdx.x;
        const unsigned chw  = quad * 4u;
        const unsigned c    = chw / HW;
        const unsigned hw   = chw - c * HW;

        // read cw once, pack step() into two bitmasks (bit = f*4 + px)
        unsigned mk0 = 0u, mk1 = 0u;
#pragma unroll
        for (int f = 0; f < Fn; ++f) {
            const f4* p = reinterpret_cast<const f4*>(cw + (size_t)f * (CHW * 2u) + (size_t)quad * 8u);
            f4 a = p[0];   // px0k0, px0k1, px1k0, px1k1
            f4 d = p[1];   // px2k0, px2k1, px3k0, px3k1
            mk0 |= (a.x > 0.f ? 1u : 0u) << (f * 4 + 0);
            mk0 |= (a.z > 0.f ? 1u : 0u) << (f * 4 + 1);
            mk0 |= (d.x > 0.f ? 1u : 0u) << (f * 4 + 2);
            mk0 |= (d.z > 0.f ? 1u : 0u) << (f * 4 + 3);
            mk1 |= (a.y > 0.f ? 1u : 0u) << (f * 4 + 0);
            mk1 |= (a.w > 0.f ? 1u : 0u) << (f * 4 + 1);
            mk1 |= (d.y > 0.f ? 1u : 0u) << (f * 4 + 2);
            mk1 |= (d.w > 0.f ? 1u : 0u) << (f * 4 + 3);
        }

        float* out0 = out;                 // ce_blur_img_noisy (noise <= 1e-8, negligible)
        float* out2 = out + OUT0 + OUT1;   // ce_blur_img
        const float inv = 0.125f;

#pragma unroll
        for (int b = 0; b < Bn; ++b) {
            f4 v[Fn];
#pragma unroll
            for (int f = 0; f < Fn; ++f)
                v[f] = *reinterpret_cast<const f4*>(frames + (size_t)(b * Fn + f) * CHW + chw);

            float sx = 0.f, sy = 0.f, sz = 0.f, sw = 0.f;   // sum over f
            float ax = 0.f, ay = 0.f, az = 0.f, aw = 0.f;   // weighted k=0
            float bx = 0.f, by = 0.f, bz = 0.f, bw = 0.f;   // weighted k=1
#pragma unroll
            for (int f = 0; f < Fn; ++f) {
                const float c00 = (mk0 >> (f * 4 + 0)) & 1u ? 1.f : 0.f;
                const float c01 = (mk0 >> (f * 4 + 1)) & 1u ? 1.f : 0.f;
                const float c02 = (mk0 >> (f * 4 + 2)) & 1u ? 1.f : 0.f;
                const float c03 = (mk0 >> (f * 4 + 3)) & 1u ? 1.f : 0.f;
                const float c10 = (mk1 >> (f * 4 + 0)) & 1u ? 1.f : 0.f;
                const float c11 = (mk1 >> (f * 4 + 1)) & 1u ? 1.f : 0.f;
                const float c12 = (mk1 >> (f * 4 + 2)) & 1u ? 1.f : 0.f;
                const float c13 = (mk1 >> (f * 4 + 3)) & 1u ? 1.f : 0.f;
                sx += v[f].x; sy += v[f].y; sz += v[f].z; sw += v[f].w;
                ax += v[f].x * c00;  ay += v[f].y * c01;  az += v[f].z * c02;  aw += v[f].w * c03;
                bx += v[f].x * c10;  by += v[f].y * c11;  bz += v[f].z * c12;  bw += v[f].w * c13;
            }
            sx *= inv; sy *= inv; sz *= inv; sw *= inv;
            ax *= inv; ay *= inv; az *= inv; aw *= inv;
            bx *= inv; by *= inv; bz *= inv; bw *= inv;

            f4 wk0 = {ax, ay, az, aw};
            f4 wk1 = {bx, by, bz, bw};
            f4 ck0 = {sx - ax, sy - ay, sz - az, sw - aw};
            f4 ck1 = {sx - bx, sy - by, sz - bz, sw - bw};

            // channel layout: ch = k*6 + s*3 + c  (s=0 weighted, s=1 comp)
            const unsigned base = (unsigned)b * 12u * HW + hw;
            *reinterpret_cast<f4*>(out0 + base + (0u + c) * HW) = wk0;
            *reinterpret_cast<f4*>(out0 + base + (3u + c) * HW) = ck0;
            *reinterpret_cast<f4*>(out0 + base + (6u + c) * HW) = wk1;
            *reinterpret_cast<f4*>(out0 + base + (9u + c) * HW) = ck1;

            *reinterpret_cast<f4*>(out2 + base + (0u + c) * HW) = wk0;
            *reinterpret_cast<f4*>(out2 + base + (3u + c) * HW) = ck0;
            *reinterpret_cast<f4*>(out2 + base + (6u + c) * HW) = wk1;
            *reinterpret_cast<f4*>(out2 + base + (9u + c) * HW) = ck1;
        }
    } else {
        // ----------------- bcast slice -----------------
        const unsigned r    = bid - XB;
        const unsigned f    = r / XB;            // 0..7
        const unsigned x    = r - f * XB;
        const unsigned quad = x * 256u + threadIdx.x;

        const f4* p = reinterpret_cast<const f4*>(cw + (size_t)f * (CHW * 2u) + (size_t)quad * 8u);
        const f4 a = p[0];
        const f4 d = p[1];

        f4 sa, sd;
        sa.x = a.x > 0.f ? 1.f : 0.f;  sa.y = a.y > 0.f ? 1.f : 0.f;
        sa.z = a.z > 0.f ? 1.f : 0.f;  sa.w = a.w > 0.f ? 1.f : 0.f;
        sd.x = d.x > 0.f ? 1.f : 0.f;  sd.y = d.y > 0.f ? 1.f : 0.f;
        sd.z = d.z > 0.f ? 1.f : 0.f;  sd.w = d.w > 0.f ? 1.f : 0.f;

#pragma unroll
        for (int b = 0; b < Bn; ++b) {
            f4* q = reinterpret_cast<f4*>(out1 + (size_t)(b * Fn + f) * (CHW * 2u) + (size_t)quad * 8u);
            q[0] = sa;
            q[1] = sd;
        }
    }
}

extern "C" void kernel_launch(void* const* d_in, const int* in_sizes, int n_in,
                              void* d_out, int out_size, void* d_ws, size_t ws_size,
                              hipStream_t stream) {
    const float* frames = (const float*)d_in[0];
    const float* cw     = (const float*)d_in[1];
    float* out          = (float*)d_out;

    constexpr unsigned grid = XB + XB * Fn;   // 2700 blur + 21600 bcast = 24300
    cep_fused_kernel<<<grid, 256, 0, stream>>>(frames, cw, out);
}

// Round 7
// 314.057 us; speedup vs baseline: 1.0877x; 1.0877x over previous
//
#include <hip/hip_runtime.h>

// Problem constants (from reference)
#define Fn 8
#define Bn 4

constexpr unsigned HW    = 720u * 1280u;                 // 921600
constexpr unsigned CHW   = 3u * HW;                      // 2764800
constexpr unsigned QUADS = CHW / 4u;                     // 691200
constexpr unsigned OUT0  = Bn * 12u * HW;                // ce_blur_img_noisy elements
constexpr unsigned OUT1  = (unsigned)Bn * Fn * CHW * 2u; // ce_code_up_ elements
// out2 (ce_blur_img) follows at OUT0 + OUT1

typedef float f4 __attribute__((ext_vector_type(4)));

// ---------------------------------------------------------------------------
// Kernel A: broadcast ce_code to out1 (+ optional packed bitmask to ws).
// Thread = (quad, f). All loads precede all stores: no load-after-store waits.
// ---------------------------------------------------------------------------
template<bool WRITE_MASK>
__global__ __launch_bounds__(256) void bcast_kernel(const float* __restrict__ cw,
                                                    float* __restrict__ out1,
                                                    unsigned char* __restrict__ mask) {
    const unsigned quad = blockIdx.x * 256u + threadIdx.x;   // 0..QUADS-1
    const unsigned f    = blockIdx.y;                        // 0..7

    // cw layout per f: 8 floats per quad = [p0k0,p0k1,p1k0,p1k1,p2k0,p2k1,p3k0,p3k1]
    const float* p = cw + (size_t)f * (CHW * 2u) + (size_t)quad * 8u;
    const f4 a = *reinterpret_cast<const f4*>(p);
    const f4 d = *reinterpret_cast<const f4*>(p + 4);

    f4 sa, sd;
    sa.x = a.x > 0.f ? 1.f : 0.f;  sa.y = a.y > 0.f ? 1.f : 0.f;
    sa.z = a.z > 0.f ? 1.f : 0.f;  sa.w = a.w > 0.f ? 1.f : 0.f;
    sd.x = d.x > 0.f ? 1.f : 0.f;  sd.y = d.y > 0.f ? 1.f : 0.f;
    sd.z = d.z > 0.f ? 1.f : 0.f;  sd.w = d.w > 0.f ? 1.f : 0.f;

#pragma unroll
    for (int b = 0; b < Bn; ++b) {
        f4* q = reinterpret_cast<f4*>(out1 + (size_t)(b * Fn + f) * (CHW * 2u) + (size_t)quad * 8u);
        q[0] = sa;
        q[1] = sd;
    }

    if (WRITE_MASK) {
        // bit j: j=0..3 -> k0 px0..3 ; j=4..7 -> k1 px0..3
        unsigned m = (a.x > 0.f ? 1u : 0u)
                   | (a.z > 0.f ? 2u : 0u)
                   | (d.x > 0.f ? 4u : 0u)
                   | (d.z > 0.f ? 8u : 0u)
                   | (a.y > 0.f ? 16u : 0u)
                   | (a.w > 0.f ? 32u : 0u)
                   | (d.y > 0.f ? 64u : 0u)
                   | (d.w > 0.f ? 128u : 0u);
        mask[(size_t)f * QUADS + quad] = (unsigned char)m;
    }
}

// ---------------------------------------------------------------------------
// Kernel B (mask path): blur outputs. Thread = (quad, b).
// Loads (8 mask bytes, 8 frame float4) all precede the 8 stores.
// ---------------------------------------------------------------------------
__global__ __launch_bounds__(256) void blur_mask_kernel(const float* __restrict__ frames,
                                                        const unsigned char* __restrict__ mask,
                                                        float* __restrict__ out) {
    const unsigned quad = blockIdx.x * 256u + threadIdx.x;
    const unsigned b    = blockIdx.y;
    const unsigned chw  = quad * 4u;
    const unsigned c    = chw / HW;
    const unsigned hw   = chw - c * HW;

    unsigned m[Fn];
    f4 v[Fn];
#pragma unroll
    for (int f = 0; f < Fn; ++f) {
        m[f] = mask[(size_t)f * QUADS + quad];
        v[f] = *reinterpret_cast<const f4*>(frames + (size_t)(b * Fn + f) * CHW + chw);
    }

    float sx = 0.f, sy = 0.f, sz = 0.f, sw = 0.f;   // sum over f
    float ax = 0.f, ay = 0.f, az = 0.f, aw = 0.f;   // weighted k=0
    float bx = 0.f, by = 0.f, bz = 0.f, bw = 0.f;   // weighted k=1
#pragma unroll
    for (int f = 0; f < Fn; ++f) {
        const float c00 = (m[f] & 1u)   ? 1.f : 0.f;
        const float c01 = (m[f] & 2u)   ? 1.f : 0.f;
        const float c02 = (m[f] & 4u)   ? 1.f : 0.f;
        const float c03 = (m[f] & 8u)   ? 1.f : 0.f;
        const float c10 = (m[f] & 16u)  ? 1.f : 0.f;
        const float c11 = (m[f] & 32u)  ? 1.f : 0.f;
        const float c12 = (m[f] & 64u)  ? 1.f : 0.f;
        const float c13 = (m[f] & 128u) ? 1.f : 0.f;
        sx += v[f].x; sy += v[f].y; sz += v[f].z; sw += v[f].w;
        ax += v[f].x * c00;  ay += v[f].y * c01;  az += v[f].z * c02;  aw += v[f].w * c03;
        bx += v[f].x * c10;  by += v[f].y * c11;  bz += v[f].z * c12;  bw += v[f].w * c13;
    }

    const float inv = 1.0f / (float)Fn;
    sx *= inv; sy *= inv; sz *= inv; sw *= inv;
    ax *= inv; ay *= inv; az *= inv; aw *= inv;
    bx *= inv; by *= inv; bz *= inv; bw *= inv;

    f4 wk0 = {ax, ay, az, aw};
    f4 wk1 = {bx, by, bz, bw};
    f4 ck0 = {sx - ax, sy - ay, sz - az, sw - aw};
    f4 ck1 = {sx - bx, sy - by, sz - bz, sw - bw};

    float* out0 = out;                 // ce_blur_img_noisy (noise <= 1e-8, negligible)
    float* out2 = out + OUT0 + OUT1;   // ce_blur_img

    // channel layout: ch = k*6 + s*3 + c  (s=0 weighted, s=1 comp)
    const unsigned base = b * 12u * HW + hw;
    *reinterpret_cast<f4*>(out0 + base + (0u + c) * HW) = wk0;
    *reinterpret_cast<f4*>(out0 + base + (3u + c) * HW) = ck0;
    *reinterpret_cast<f4*>(out0 + base + (6u + c) * HW) = wk1;
    *reinterpret_cast<f4*>(out0 + base + (9u + c) * HW) = ck1;

    *reinterpret_cast<f4*>(out2 + base + (0u + c) * HW) = wk0;
    *reinterpret_cast<f4*>(out2 + base + (3u + c) * HW) = ck0;
    *reinterpret_cast<f4*>(out2 + base + (6u + c) * HW) = wk1;
    *reinterpret_cast<f4*>(out2 + base + (9u + c) * HW) = ck1;
}

// ---------------------------------------------------------------------------
// Kernel B fallback (no workspace): fat thread = quad, reads cw directly once.
// ---------------------------------------------------------------------------
__global__ __launch_bounds__(256) void blur_cw_kernel(const float* __restrict__ frames,
                                                      const float* __restrict__ cw,
                                                      float* __restrict__ out) {
    const unsigned quad = blockIdx.x * 256u + threadIdx.x;
    const unsigned chw  = quad * 4u;
    const unsigned c    = chw / HW;
    const unsigned hw   = chw - c * HW;

    f4 ci[Fn][2];
#pragma unroll
    for (int f = 0; f < Fn; ++f) {
        const f4* p = reinterpret_cast<const f4*>(cw + (size_t)f * (CHW * 2u) + (size_t)quad * 8u);
        f4 a = p[0], d = p[1];
        f4 sa, sd;
        sa.x = a.x > 0.f ? 1.f : 0.f;  sa.y = a.y > 0.f ? 1.f : 0.f;
        sa.z = a.z > 0.f ? 1.f : 0.f;  sa.w = a.w > 0.f ? 1.f : 0.f;
        sd.x = d.x > 0.f ? 1.f : 0.f;  sd.y = d.y > 0.f ? 1.f : 0.f;
        sd.z = d.z > 0.f ? 1.f : 0.f;  sd.w = d.w > 0.f ? 1.f : 0.f;
        ci[f][0] = sa;
        ci[f][1] = sd;
    }

    float* out0 = out;
    float* out2 = out + OUT0 + OUT1;
    const float inv = 1.0f / (float)Fn;

#pragma unroll
    for (int b = 0; b < Bn; ++b) {
        float sx = 0.f, sy = 0.f, sz = 0.f, sw = 0.f;
        float ax = 0.f, ay = 0.f, az = 0.f, aw = 0.f;
        float bx = 0.f, by = 0.f, bz = 0.f, bw = 0.f;
#pragma unroll
        for (int f = 0; f < Fn; ++f) {
            f4 v = *reinterpret_cast<const f4*>(frames + (size_t)(b * Fn + f) * CHW + chw);
            sx += v.x; sy += v.y; sz += v.z; sw += v.w;
            ax += v.x * ci[f][0].x;  ay += v.y * ci[f][0].z;
            az += v.z * ci[f][1].x;  aw += v.w * ci[f][1].z;
            bx += v.x * ci[f][0].y;  by += v.y * ci[f][0].w;
            bz += v.z * ci[f][1].y;  bw += v.w * ci[f][1].w;
        }
        sx *= inv; sy *= inv; sz *= inv; sw *= inv;
        ax *= inv; ay *= inv; az *= inv; aw *= inv;
        bx *= inv; by *= inv; bz *= inv; bw *= inv;

        f4 wk0 = {ax, ay, az, aw};
        f4 wk1 = {bx, by, bz, bw};
        f4 ck0 = {sx - ax, sy - ay, sz - az, sw - aw};
        f4 ck1 = {sx - bx, sy - by, sz - bz, sw - bw};

        const unsigned base = b * 12u * HW + hw;
        *reinterpret_cast<f4*>(out0 + base + (0u + c) * HW) = wk0;
        *reinterpret_cast<f4*>(out0 + base + (3u + c) * HW) = ck0;
        *reinterpret_cast<f4*>(out0 + base + (6u + c) * HW) = wk1;
        *reinterpret_cast<f4*>(out0 + base + (9u + c) * HW) = ck1;
        *reinterpret_cast<f4*>(out2 + base + (0u + c) * HW) = wk0;
        *reinterpret_cast<f4*>(out2 + base + (3u + c) * HW) = ck0;
        *reinterpret_cast<f4*>(out2 + base + (6u + c) * HW) = wk1;
        *reinterpret_cast<f4*>(out2 + base + (9u + c) * HW) = ck1;
    }
}

extern "C" void kernel_launch(void* const* d_in, const int* in_sizes, int n_in,
                              void* d_out, int out_size, void* d_ws, size_t ws_size,
                              hipStream_t stream) {
    const float* frames = (const float*)d_in[0];
    const float* cw     = (const float*)d_in[1];
    float* out          = (float*)d_out;
    unsigned char* mask = (unsigned char*)d_ws;

    constexpr unsigned xblocks = QUADS / 256u;   // 2700 (exact)
    const bool use_mask = ws_size >= (size_t)QUADS * Fn;   // 5.53 MB

    if (use_mask) {
        bcast_kernel<true><<<dim3(xblocks, Fn), 256, 0, stream>>>(cw, out + OUT0, mask);
        blur_mask_kernel<<<dim3(xblocks, Bn), 256, 0, stream>>>(frames, mask, out);
    } else {
        bcast_kernel<false><<<dim3(xblocks, Fn), 256, 0, stream>>>(cw, out + OUT0, mask);
        blur_cw_kernel<<<xblocks, 256, 0, stream>>>(frames, cw, out);
    }
}